// Round 1
// baseline (5988.897 us; speedup 1.0000x reference)
//
#include <hip/hip_runtime.h>
#include <hip/hip_bf16.h>

#define BB 4096
#define INF 8192
#define SS 128
#define HH 256

typedef __attribute__((ext_vector_type(8))) short short8;
typedef __attribute__((ext_vector_type(4))) float f32x4;

__device__ __forceinline__ float sigm(float x) { return 1.f / (1.f + __expf(-x)); }
__device__ __forceinline__ float tanh_fast(float x) {
    float cx = fminf(15.f, fmaxf(-15.f, x));
    float e = __expf(2.f * cx);
    return (e - 1.f) / (e + 1.f);
}
__device__ __forceinline__ unsigned short f2bf(float f) {
    __hip_bfloat16 b = __float2bfloat16(f);
    return *(unsigned short*)&b;
}
__device__ __forceinline__ float bf2f(unsigned short u) {
    __hip_bfloat16 b = *(__hip_bfloat16*)&u;
    return __bfloat162float(b);
}

#define GLD(g, l) __builtin_amdgcn_global_load_lds(                              \
        (const __attribute__((address_space(1))) void*)(g),                      \
        (__attribute__((address_space(3))) void*)(l), 16, 0, 0)

// ---- BatchNorm stats ------------------------------------------------------
__global__ __launch_bounds__(256) void bn_partial(const float* __restrict__ x,
                                                  float* __restrict__ colsum,
                                                  float* __restrict__ colsumsq) {
    int j = blockIdx.x * 256 + threadIdx.x;
    int r0 = blockIdx.y * 256;
    float s1 = 0.f, s2 = 0.f;
    for (int r = r0; r < r0 + 256; ++r) {
        float v = x[(size_t)r * INF + j];
        s1 += v;
        s2 += v * v;
    }
    atomicAdd(&colsum[j], s1);
    atomicAdd(&colsumsq[j], s2);
}

__global__ __launch_bounds__(256) void bn_finalize(const float* __restrict__ colsum,
                                                   const float* __restrict__ colsumsq,
                                                   const float* __restrict__ gamma,
                                                   const float* __restrict__ beta,
                                                   float* __restrict__ scl,
                                                   float* __restrict__ shf) {
    int j = blockIdx.x * 256 + threadIdx.x;
    float mean = colsum[j] * (1.f / BB);
    float var = colsumsq[j] * (1.f / BB) - mean * mean;
    float a = gamma[j] * rsqrtf(var + 1e-5f);
    scl[j] = a;
    shf[j] = beta[j] - mean * a;
}

// ---- split fp32 -> bf16 hi/lo with BN affine fused ------------------------
__global__ __launch_bounds__(256) void split_x(const float* __restrict__ x,
                                               const float* __restrict__ scl,
                                               const float* __restrict__ shf,
                                               unsigned short* __restrict__ hi,
                                               unsigned short* __restrict__ lo) {
    size_t i = ((size_t)blockIdx.x * 256 + threadIdx.x) * 4;
    float4 v = *(const float4*)(x + i);
    int col = (int)(i & (INF - 1));
    float4 s = *(const float4*)(scl + col);
    float4 h = *(const float4*)(shf + col);
    float f[4] = {fmaf(v.x, s.x, h.x), fmaf(v.y, s.y, h.y),
                  fmaf(v.z, s.z, h.z), fmaf(v.w, s.w, h.w)};
    ushort4 hv, lv;
    unsigned short* hp = (unsigned short*)&hv;
    unsigned short* lp = (unsigned short*)&lv;
#pragma unroll
    for (int k = 0; k < 4; ++k) {
        unsigned short hb = f2bf(f[k]);
        hp[k] = hb;
        lp[k] = f2bf(f[k] - bf2f(hb));
    }
    *(ushort4*)(hi + i) = hv;
    *(ushort4*)(lo + i) = lv;
}

__global__ __launch_bounds__(256) void split_w(const float* __restrict__ w,
                                               unsigned short* __restrict__ hi,
                                               unsigned short* __restrict__ lo) {
    size_t i = ((size_t)blockIdx.x * 256 + threadIdx.x) * 4;
    float4 v = *(const float4*)(w + i);
    float f[4] = {v.x, v.y, v.z, v.w};
    ushort4 hv, lv;
    unsigned short* hp = (unsigned short*)&hv;
    unsigned short* lp = (unsigned short*)&lv;
#pragma unroll
    for (int k = 0; k < 4; ++k) {
        unsigned short hb = f2bf(f[k]);
        hp[k] = hb;
        lp[k] = f2bf(f[k] - bf2f(hb));
    }
    *(ushort4*)(hi + i) = hv;
    *(ushort4*)(lo + i) = lv;
}

// ---- pack W_ih|W_hh into gate-interleaved rows + split --------------------
__global__ __launch_bounds__(128) void pack_w(const float* __restrict__ Wih,
                                              const float* __restrict__ Whh,
                                              const float* __restrict__ bih,
                                              const float* __restrict__ bhh,
                                              unsigned short* __restrict__ Wch,
                                              unsigned short* __restrict__ Wcl,
                                              float* __restrict__ biascat) {
    int r = blockIdx.x;  // 0..1023
    int c = r >> 2, g = r & 3;
    int t = threadIdx.x;
    if (t == 0) biascat[r] = bih[g * 256 + c] + bhh[g * 256 + c];
    if (t >= 80) return;
    float4 v;
    if (t < 16)
        v = *(const float4*)(Wih + (size_t)(g * 256 + c) * 64 + t * 4);
    else
        v = *(const float4*)(Whh + (size_t)(g * 256 + c) * 256 + (t - 16) * 4);
    float f[4] = {v.x, v.y, v.z, v.w};
    ushort4 hv, lv;
    unsigned short* hp = (unsigned short*)&hv;
    unsigned short* lp = (unsigned short*)&lv;
#pragma unroll
    for (int k = 0; k < 4; ++k) {
        unsigned short hb = f2bf(f[k]);
        hp[k] = hb;
        lp[k] = f2bf(f[k] - bf2f(hb));
    }
    *(ushort4*)(Wch + (size_t)r * 320 + t * 4) = hv;
    *(ushort4*)(Wcl + (size_t)r * 320 + t * 4) = lv;
}

// ---- big GEMM: proj = xn @ W_in^T, split-bf16 as virtual K'=3K ------------
// 256x256 tile, BK=32, ring-4 LDS, phase-interleaved schedule with counted
// vmcnt (T2+T3+T4+T5). k-tile t: seg=t%3 -> (Ah,Bh),(Al,Bh),(Ah,Bl).
// LDS stage layout (per ring, 256 rows x 32 k bf16):
//   line = r>>1, slot = (kg | (r&1)<<2) ^ (line&7), byte = line*128+slot*16+(k&7)*2
// global_load_lds writes linearly; the inverse swizzle is applied to the
// global SOURCE address (rule: linear dest + inv-swz source + swz read).
__global__ __launch_bounds__(512, 2) void gemm8(
    const unsigned short* __restrict__ Ah, const unsigned short* __restrict__ Al,
    const unsigned short* __restrict__ Bh, const unsigned short* __restrict__ Bl,
    unsigned short* __restrict__ projsplit) {
    __shared__ unsigned short As[32768];  // 4 rings x 8192 ushorts = 64 KiB
    __shared__ unsigned short Bs[32768];
    const int tid = threadIdx.x;
    const int lane = tid & 63, wid = tid >> 6;
    const int wmi = wid >> 2, wni = wid & 3;       // wave grid 2(M) x 4(N)
    const int l15 = lane & 15, q = lane >> 4;

    // XCD-aware swizzle (512 wgs, 64/XCD): each XCD gets 4 bx columns x 16 by
    const int bid = blockIdx.x;
    const int wg = ((bid & 7) << 6) | (bid >> 3);
    const int bx = wg >> 4, by = wg & 15;
    const int row0 = by << 8, col0 = bx << 8;

    // staging per-thread constants (inverse-swizzled source mapping)
    const int slot = (tid & 7) ^ ((tid >> 3) & 7);
    const int rr = ((tid >> 3) << 1) | (slot >> 2);  // 0..127 within stmt
    const int kgo = (slot & 3) << 3;                 // k offset 0/8/16/24
    const int wbase = wid << 9;                      // wave chunk (ushorts)

    // swizzled ds_read base (ushort offset within a ring, frag-base adds rb*32)
    const int dsb = ((l15 >> 1) << 6) + (((q | ((l15 & 1) << 2)) ^ (l15 >> 1)) << 3);

#define STAGE_A(srcp, ks, ring)                                                   \
    do {                                                                          \
        const unsigned short* _g = (srcp) + (size_t)(row0 + rr) * INF + (ks) + kgo; \
        GLD(_g, &As[((ring) << 13) + wbase]);                                     \
        GLD(_g + (size_t)128 * INF, &As[((ring) << 13) + 4096 + wbase]);          \
    } while (0)
#define STAGE_B(srcp, ks, ring)                                                   \
    do {                                                                          \
        const unsigned short* _g = (srcp) + (size_t)(col0 + rr) * INF + (ks) + kgo; \
        GLD(_g, &Bs[((ring) << 13) + wbase]);                                     \
        GLD(_g + (size_t)128 * INF, &Bs[((ring) << 13) + 4096 + wbase]);          \
    } while (0)
#define LDA4(d, i2, rgofs)                                                        \
    do {                                                                          \
        d[0] = *(const short8*)&As[(rgofs) + wmi * 4096 + (i2)*2048 + 0 * 512 + dsb]; \
        d[1] = *(const short8*)&As[(rgofs) + wmi * 4096 + (i2)*2048 + 1 * 512 + dsb]; \
        d[2] = *(const short8*)&As[(rgofs) + wmi * 4096 + (i2)*2048 + 2 * 512 + dsb]; \
        d[3] = *(const short8*)&As[(rgofs) + wmi * 4096 + (i2)*2048 + 3 * 512 + dsb]; \
    } while (0)
#define LDB4(d, rgofs)                                                            \
    do {                                                                          \
        d[0] = *(const short8*)&Bs[(rgofs) + wni * 2048 + 0 * 512 + dsb];         \
        d[1] = *(const short8*)&Bs[(rgofs) + wni * 2048 + 1 * 512 + dsb];         \
        d[2] = *(const short8*)&Bs[(rgofs) + wni * 2048 + 2 * 512 + dsb];         \
        d[3] = *(const short8*)&Bs[(rgofs) + wni * 2048 + 3 * 512 + dsb];         \
    } while (0)
#define MFMA16(accx)                                                              \
    do {                                                                          \
        __builtin_amdgcn_s_setprio(1);                                            \
        _Pragma("unroll") for (int i_ = 0; i_ < 4; ++i_)                          \
            _Pragma("unroll") for (int j_ = 0; j_ < 4; ++j_)                      \
                accx[i_][j_] = __builtin_amdgcn_mfma_f32_16x16x32_bf16(           \
                    a[i_], b[j_], accx[i_][j_], 0, 0, 0);                         \
        __builtin_amdgcn_s_setprio(0);                                            \
    } while (0)

    f32x4 acc0[4][4], acc1[4][4];
#pragma unroll
    for (int i = 0; i < 4; ++i)
#pragma unroll
        for (int j = 0; j < 4; ++j) {
            acc0[i][j] = (f32x4){0.f, 0.f, 0.f, 0.f};
            acc1[i][j] = (f32x4){0.f, 0.f, 0.f, 0.f};
        }

    short8 a[4], b[4];

    // prologue: stage tiles 0,1,2 (segs 0,1,2 of source k-tile 0)
    STAGE_A(Ah, 0, 0);
    STAGE_B(Bh, 0, 0);
    STAGE_A(Al, 0, 1);
    STAGE_B(Bh, 0, 1);
    STAGE_A(Ah, 0, 2);
    STAGE_B(Bl, 0, 2);
    asm volatile("s_waitcnt vmcnt(8)" ::: "memory");  // tile 0 landed
    __builtin_amdgcn_s_barrier();

    // 768 virtual k-tiles; main loop stages t+3, last 3 handled in drain
    int seg3 = 0, ks3 = 32;  // seg/ksrc for tile t+3 (t=0 -> tile 3)
    for (int t = 0; t < 765; ++t) {
        const int rg = (t & 3) << 13;
        const int sr = (t + 3) & 3;
        const unsigned short* sA = (seg3 == 1) ? Al : Ah;
        const unsigned short* sB = (seg3 == 2) ? Bl : Bh;
        // phase 0: A(i2=0) + B frags, prefetch A stmts of tile t+3
        LDA4(a, 0, rg);
        LDB4(b, rg);
        STAGE_A(sA, ks3, sr);
        __builtin_amdgcn_s_barrier();
        asm volatile("s_waitcnt lgkmcnt(0)" ::: "memory");
        __builtin_amdgcn_sched_barrier(0);
        MFMA16(acc0);
        __builtin_amdgcn_s_barrier();
        // phase 1: A(i2=1) frags (B reused in regs), prefetch B stmts
        LDA4(a, 1, rg);
        STAGE_B(sB, ks3, sr);
        __builtin_amdgcn_s_barrier();
        asm volatile("s_waitcnt lgkmcnt(0)" ::: "memory");
        __builtin_amdgcn_sched_barrier(0);
        MFMA16(acc1);
        asm volatile("s_waitcnt vmcnt(8)" ::: "memory");  // tile t+1 ready
        __builtin_amdgcn_s_barrier();
        if (++seg3 == 3) { seg3 = 0; ks3 += 32; }
    }
    // drain: tiles 765..767 already staged; no prefetch
    asm volatile("s_waitcnt vmcnt(0)" ::: "memory");
    __builtin_amdgcn_s_barrier();
    for (int t = 765; t < 768; ++t) {
        const int rg = (t & 3) << 13;
        LDA4(a, 0, rg);
        LDB4(b, rg);
        asm volatile("s_waitcnt lgkmcnt(0)" ::: "memory");
        __builtin_amdgcn_sched_barrier(0);
        MFMA16(acc0);
        __builtin_amdgcn_s_barrier();
        LDA4(a, 1, rg);
        asm volatile("s_waitcnt lgkmcnt(0)" ::: "memory");
        __builtin_amdgcn_sched_barrier(0);
        MFMA16(acc1);
        __builtin_amdgcn_s_barrier();
    }

    // epilogue: split-bf16 write to slice-major projsplit
#pragma unroll
    for (int i = 0; i < 4; ++i)
#pragma unroll
        for (int j = 0; j < 4; ++j) {
            int col = col0 + wni * 64 + j * 16 + l15;
            int slice = col >> 6, c6 = col & 63;
            unsigned short* ps = projsplit + (size_t)slice * 524288;
#pragma unroll
            for (int r = 0; r < 4; ++r) {
                int row = row0 + wmi * 128 + i * 16 + q * 4 + r;
                float v = acc0[i][j][r];
                unsigned short hb = f2bf(v);
                ps[row * 64 + c6] = hb;
                ps[262144 + row * 64 + c6] = f2bf(v - bf2f(hb));
                row += 64;
                v = acc1[i][j][r];
                hb = f2bf(v);
                ps[row * 64 + c6] = hb;
                ps[262144 + row * 64 + c6] = f2bf(v - bf2f(hb));
            }
        }
#undef STAGE_A
#undef STAGE_B
#undef LDA4
#undef LDB4
#undef MFMA16
}

// ---- one LSTM step: M=4096 x N=1024 gates GEMM (K=320) + fused cell ------
__global__ __launch_bounds__(256) void lstm_step_mfma(
    const unsigned short* __restrict__ projsplit,
    const unsigned short* __restrict__ Wch, const unsigned short* __restrict__ Wcl,
    const float* __restrict__ biascat,
    const unsigned short* __restrict__ hin_h, const unsigned short* __restrict__ hin_l,
    unsigned short* __restrict__ hout_h, unsigned short* __restrict__ hout_l,
    float* __restrict__ cbuf, float* __restrict__ hs, int s) {
    __shared__ unsigned short AsH[4096], AsL[4096], BsH[4096], BsL[4096];
    __shared__ float gates[128][132];
    __shared__ float sbias[128];
    const int tid = threadIdx.x;
    const int lane = tid & 63, wid = tid >> 6;
    const int row0 = (blockIdx.x & 31) << 7;
    const int col0 = (blockIdx.x >> 5) << 7;
    if (tid < 128) sbias[tid] = biascat[col0 + tid];

    const int wm = (wid & 1) << 6, wn = (wid >> 1) << 6;
    const int q = lane >> 4, l15 = lane & 15;
    const int s0 = wid * 128 + lane, s1 = s0 + 64;
    const int r0 = s0 >> 2, k0 = (((s0 & 3) ^ ((r0 >> 1) & 3)) << 3);
    const int r1 = s1 >> 2, k1 = (((s1 & 3) ^ ((r1 >> 1) & 3)) << 3);
    const int lb0 = (wid * 128) * 8, lb1 = lb0 + 512;

    const unsigned short* psl = projsplit + (size_t)s * 524288;

    f32x4 acc[4][4];
#pragma unroll
    for (int i = 0; i < 4; ++i)
#pragma unroll
        for (int j = 0; j < 4; ++j) acc[i][j] = (f32x4){0.f, 0.f, 0.f, 0.f};

    for (int kb = 0; kb < 10; ++kb) {
        __syncthreads();
        const unsigned short *pah0, *pal0, *pah1, *pal1;
        if (kb < 2) {
            int off0 = (row0 + r0) * 64 + kb * 32 + k0;
            int off1 = (row0 + r1) * 64 + kb * 32 + k1;
            pah0 = psl + off0;          pal0 = psl + 262144 + off0;
            pah1 = psl + off1;          pal1 = psl + 262144 + off1;
        } else {
            int kh = kb * 32 - 64;
            int off0 = (row0 + r0) * HH + kh + k0;
            int off1 = (row0 + r1) * HH + kh + k1;
            pah0 = hin_h + off0;        pal0 = hin_l + off0;
            pah1 = hin_h + off1;        pal1 = hin_l + off1;
        }
        const unsigned short* pbh0 = Wch + (size_t)(col0 + r0) * 320 + kb * 32 + k0;
        const unsigned short* pbh1 = Wch + (size_t)(col0 + r1) * 320 + kb * 32 + k1;
        const unsigned short* pbl0 = Wcl + (size_t)(col0 + r0) * 320 + kb * 32 + k0;
        const unsigned short* pbl1 = Wcl + (size_t)(col0 + r1) * 320 + kb * 32 + k1;
        GLD(pah0, &AsH[lb0]);
        GLD(pah1, &AsH[lb1]);
        GLD(pal0, &AsL[lb0]);
        GLD(pal1, &AsL[lb1]);
        GLD(pbh0, &BsH[lb0]);
        GLD(pbh1, &BsH[lb1]);
        GLD(pbl0, &BsL[lb0]);
        GLD(pbl1, &BsL[lb1]);
        __syncthreads();

        short8 ahf[4], alf[4], bhf[4], blf[4];
#pragma unroll
        for (int i = 0; i < 4; ++i) {
            int ra = wm + i * 16 + l15;
            int offa = ra * 32 + ((q ^ ((ra >> 1) & 3)) << 3);
            ahf[i] = *(const short8*)&AsH[offa];
            alf[i] = *(const short8*)&AsL[offa];
            int rb = wn + i * 16 + l15;
            int offb = rb * 32 + ((q ^ ((rb >> 1) & 3)) << 3);
            bhf[i] = *(const short8*)&BsH[offb];
            blf[i] = *(const short8*)&BsL[offb];
        }
#pragma unroll
        for (int i = 0; i < 4; ++i)
#pragma unroll
            for (int j = 0; j < 4; ++j) {
                acc[i][j] = __builtin_amdgcn_mfma_f32_16x16x32_bf16(ahf[i], bhf[j], acc[i][j], 0, 0, 0);
                acc[i][j] = __builtin_amdgcn_mfma_f32_16x16x32_bf16(ahf[i], blf[j], acc[i][j], 0, 0, 0);
                acc[i][j] = __builtin_amdgcn_mfma_f32_16x16x32_bf16(alf[i], bhf[j], acc[i][j], 0, 0, 0);
            }
    }

    __syncthreads();
#pragma unroll
    for (int i = 0; i < 4; ++i)
#pragma unroll
        for (int j = 0; j < 4; ++j)
#pragma unroll
            for (int r = 0; r < 4; ++r)
                gates[wm + i * 16 + q * 4 + r][wn + j * 16 + l15] = acc[i][j][r];
    __syncthreads();

    const int hc = tid & 31, rg = tid >> 5;
    const int hbase = col0 >> 2;
#pragma unroll
    for (int rr = 0; rr < 16; ++rr) {
        int row = rg * 16 + rr;
        int b = row0 + row;
        float4 g4 = *(const float4*)&gates[row][4 * hc];
        float4 b4 = *(const float4*)&sbias[4 * hc];
        size_t ci = (size_t)b * HH + hbase + hc;
        float cold = (s > 0) ? cbuf[ci] : 0.f;
        float i_ = sigm(g4.x + b4.x);
        float f_ = sigm(g4.y + b4.y);
        float g_ = tanh_fast(g4.z + b4.z);
        float o_ = sigm(g4.w + b4.w);
        float cn = fmaf(f_, cold, i_ * g_);
        float hn = o_ * tanh_fast(cn);
        cbuf[ci] = cn;
        hs[(size_t)s * (BB * HH) + ci] = hn;
        unsigned short hb = f2bf(hn);
        hout_h[ci] = hb;
        hout_l[ci] = f2bf(hn - bf2f(hb));
    }
}

// ---- q[b,s] = hs[s,b,:] . W_out ------------------------------------------
__global__ __launch_bounds__(256) void q_kernel(const float* __restrict__ hs,
                                                const float* __restrict__ wout,
                                                float* __restrict__ q) {
    int wid = threadIdx.x >> 6, lane = threadIdx.x & 63;
    int p = (blockIdx.x << 2) + wid;
    int b = p & (BB - 1), s = p >> 12;
    const float* hp = hs + ((size_t)s * BB + b) * HH + (lane << 2);
    float4 h4 = *(const float4*)hp;
    float4 w4 = *(const float4*)(wout + (lane << 2));
    float v = h4.x * w4.x + h4.y * w4.y + h4.z * w4.z + h4.w * w4.w;
#pragma unroll
    for (int off = 32; off; off >>= 1) v += __shfl_xor(v, off);
    if (lane == 0) q[b * SS + s] = v;
}

// ---- attention logits, split-K (8 chunks of K=4096) ----------------------
__global__ __launch_bounds__(256) void attn_part(const float* __restrict__ hs,
                                                 const float* __restrict__ Wta,
                                                 float* __restrict__ part) {
    __shared__ float As[16][68];
    __shared__ float Bs[16][132];
    const int tid = threadIdx.x;
    const int tx = tid & 15, ty = tid >> 4;
    const int row0 = blockIdx.x << 6;
    const int jc = blockIdx.y;
    const int lrA = tid >> 2, lkA = (tid & 3) << 2;
    const int lrB = tid >> 1, lkB = (tid & 1) << 3;

    float acc[4][8];
#pragma unroll
    for (int i = 0; i < 4; ++i)
#pragma unroll
        for (int j = 0; j < 8; ++j) acc[i][j] = 0.f;

    for (int kb = 0; kb < 256; ++kb) {
        int k0 = (jc << 12) + (kb << 4);
        int sidx = k0 >> 8, h0 = k0 & 255;
        float4 av = *(const float4*)(hs + ((size_t)sidx * BB + row0 + lrA) * HH + h0 + lkA);
        const float* wp = Wta + (size_t)lrB * (SS * HH) + k0 + lkB;
        float4 bv0 = *(const float4*)wp;
        float4 bv1 = *(const float4*)(wp + 4);
        __syncthreads();
        As[lkA + 0][lrA] = av.x;
        As[lkA + 1][lrA] = av.y;
        As[lkA + 2][lrA] = av.z;
        As[lkA + 3][lrA] = av.w;
        Bs[lkB + 0][lrB] = bv0.x;
        Bs[lkB + 1][lrB] = bv0.y;
        Bs[lkB + 2][lrB] = bv0.z;
        Bs[lkB + 3][lrB] = bv0.w;
        Bs[lkB + 4][lrB] = bv1.x;
        Bs[lkB + 5][lrB] = bv1.y;
        Bs[lkB + 6][lrB] = bv1.z;
        Bs[lkB + 7][lrB] = bv1.w;
        __syncthreads();
#pragma unroll
        for (int k = 0; k < 16; ++k) {
            float4 af = *(const float4*)&As[k][ty << 2];
            float4 b0 = *(const float4*)&Bs[k][tx << 2];
            float4 b1 = *(const float4*)&Bs[k][64 + (tx << 2)];
            float ar[4] = {af.x, af.y, af.z, af.w};
            float br[8] = {b0.x, b0.y, b0.z, b0.w, b1.x, b1.y, b1.z, b1.w};
#pragma unroll
            for (int i = 0; i < 4; ++i)
#pragma unroll
                for (int j = 0; j < 8; ++j)
                    acc[i][j] = fmaf(ar[i], br[j], acc[i][j]);
        }
    }
#pragma unroll
    for (int i = 0; i < 4; ++i) {
        int b = row0 + (ty << 2) + i;
        float* pp = part + ((size_t)jc * BB + b) * SS;
        float4 o0 = {acc[i][0], acc[i][1], acc[i][2], acc[i][3]};
        float4 o1 = {acc[i][4], acc[i][5], acc[i][6], acc[i][7]};
        *(float4*)(pp + (tx << 2)) = o0;
        *(float4*)(pp + 64 + (tx << 2)) = o1;
    }
}

// ---- relu -> softmax -> weighted sum of q --------------------------------
__global__ __launch_bounds__(256) void attn_finalize(const float* __restrict__ part,
                                                     const float* __restrict__ b_ta,
                                                     const float* __restrict__ q,
                                                     float* __restrict__ out) {
    int wid = threadIdx.x >> 6, lane = threadIdx.x & 63;
    int b = (blockIdx.x << 2) + wid;
    float l0 = b_ta[lane], l1 = b_ta[lane + 64];
#pragma unroll
    for (int j = 0; j < 8; ++j) {
        const float* pp = part + ((size_t)j * BB + b) * SS;
        l0 += pp[lane];
        l1 += pp[lane + 64];
    }
    l0 = fmaxf(l0, 0.f);
    l1 = fmaxf(l1, 0.f);
    float mx = fmaxf(l0, l1);
#pragma unroll
    for (int off = 32; off; off >>= 1) mx = fmaxf(mx, __shfl_xor(mx, off));
    float e0 = __expf(l0 - mx), e1 = __expf(l1 - mx);
    float num = fmaf(e0, q[b * SS + lane], e1 * q[b * SS + lane + 64]);
    float den = e0 + e1;
#pragma unroll
    for (int off = 32; off; off >>= 1) {
        num += __shfl_xor(num, off);
        den += __shfl_xor(den, off);
    }
    if (lane == 0) out[b] = num / den;
}

extern "C" void kernel_launch(void* const* d_in, const int* in_sizes, int n_in,
                              void* d_out, int out_size, void* d_ws, size_t ws_size,
                              hipStream_t stream) {
    const float* x     = (const float*)d_in[0];
    const float* gamma = (const float*)d_in[1];
    const float* beta_ = (const float*)d_in[2];
    const float* W_in  = (const float*)d_in[3];
    const float* W_ih  = (const float*)d_in[4];
    const float* b_ih  = (const float*)d_in[5];
    const float* W_hh  = (const float*)d_in[6];
    const float* b_hh  = (const float*)d_in[7];
    const float* W_ta  = (const float*)d_in[8];
    const float* b_ta  = (const float*)d_in[9];
    const float* W_out = (const float*)d_in[10];
    float* out = (float*)d_out;

    float* ws = (float*)d_ws;
    float* colsum   = ws;                 // 8192
    float* colsumsq = ws + 8192;          // 8192
    float* scl      = ws + 16384;         // 8192
    float* shf      = ws + 24576;         // 8192
    float* biascat  = ws + 32768;         // 1024
    float* qbuf     = ws + 33792;         // 524288
    float* part     = ws + 558080;        // 8*4096*128 = 4194304
    float* cbuf     = ws + 4752384;       // 1048576
    unsigned short* Wch   = (unsigned short*)(ws + 5800960);  // 327680 us
    unsigned short* Wcl   = (unsigned short*)(ws + 5964800);  // 327680 us
    unsigned short* hsp0h = (unsigned short*)(ws + 6128640);  // 1048576 us
    unsigned short* hsp0l = (unsigned short*)(ws + 6652928);
    unsigned short* hsp1h = (unsigned short*)(ws + 7177216);
    unsigned short* hsp1l = (unsigned short*)(ws + 7701504);  // ends 8225792
    float* hs = ws + 8388608;             // 128*4096*256 floats
    unsigned short* xh = (unsigned short*)hs;        // 33554432 us
    unsigned short* xl = xh + 33554432;
    unsigned short* Wh = xl + 33554432;              // 67108864 us
    unsigned short* Wl = Wh + 67108864;              // ends at +384 MiB
    unsigned short* projsplit = (unsigned short*)(ws + 8388608 + 108003328);

    hipMemsetAsync(colsum, 0, 2 * 8192 * sizeof(float), stream);
    hipMemsetAsync(hsp0h, 0, 4194304, stream);  // hsp0h+hsp0l (h at s=0 is 0)

    bn_partial<<<dim3(32, 16), 256, 0, stream>>>(x, colsum, colsumsq);
    bn_finalize<<<32, 256, 0, stream>>>(colsum, colsumsq, gamma, beta_, scl, shf);
    split_x<<<32768, 256, 0, stream>>>(x, scl, shf, xh, xl);
    split_w<<<65536, 256, 0, stream>>>(W_in, Wh, Wl);
    pack_w<<<1024, 128, 0, stream>>>(W_ih, W_hh, b_ih, b_hh, Wch, Wcl, biascat);
    gemm8<<<512, 512, 0, stream>>>(xh, xl, Wh, Wl, projsplit);
    for (int s = 0; s < 128; ++s) {
        const unsigned short* hih = (s & 1) ? hsp1h : hsp0h;
        const unsigned short* hil = (s & 1) ? hsp1l : hsp0l;
        unsigned short* hoh = (s & 1) ? hsp0h : hsp1h;
        unsigned short* hol = (s & 1) ? hsp0l : hsp1l;
        lstm_step_mfma<<<256, 256, 0, stream>>>(projsplit, Wch, Wcl, biascat,
                                                hih, hil, hoh, hol, cbuf, hs, s);
    }
    q_kernel<<<131072, 256, 0, stream>>>(hs, W_out, qbuf);
    attn_part<<<dim3(64, 8), 256, 0, stream>>>(hs, W_ta, part);
    attn_finalize<<<1024, 256, 0, stream>>>(part, b_ta, qbuf, out);
}